// Round 9
// baseline (5960.359 us; speedup 1.0000x reference)
//
#include <hip/hip_runtime.h>
#include <cstdint>

#define NB 128   // batch
#define NS 1024  // seq len
#define NV 128   // input dim
#define NH 256   // hidden
#define CH 64    // chunk length
#define NCH (NS / CH)

typedef _Float16 f16;
typedef _Float16 h2 __attribute__((ext_vector_type(2)));
typedef uint32_t u32;

static __device__ __forceinline__ float fdot2(u32 a, u32 b, float c) {
  return __builtin_amdgcn_fdot2(__builtin_bit_cast(h2, a),
                                __builtin_bit_cast(h2, b), c, false);
}
static __device__ __forceinline__ u32 pkh(float a, float b) {  // RTN (preload)
  union { h2 h; u32 u; } cv; cv.h = h2{(f16)a, (f16)b}; return cv.u;
}
static __device__ __forceinline__ u32 pkz(float a, float b) {  // RTZ (hot path)
  return __builtin_bit_cast(u32, __builtin_amdgcn_cvt_pkrtz(a, b));
}
static __device__ __forceinline__ float sigm(float x) { return 1.f / (1.f + __expf(-x)); }
static __device__ __forceinline__ float tanh_(float x) { return 1.f - 2.f / (__expf(2.f * x) + 1.f); }

// ---------------------------------------------------------------------------
// gemm pair. waves_per_eu(2,2) HARD PIN: 8-wave block = exactly 2 waves/EU,
// so the allocator has no higher-occupancy class to chase -> weight arrays
// (gemm1: 48 uint4 req ~230 VGPR; gemm0: 32 uint4 ~170) stay resident.
// (Round-8 (512,2): allocator took 128-class and spilled ~64 VGPR to L2.)
// Bodies unchanged from round 8 (passed, absmax 1.95e-3).
// ---------------------------------------------------------------------------
__global__ __attribute__((amdgpu_flat_work_group_size(512, 512),
                          amdgpu_waves_per_eu(2, 2)))
void gemm_pair_kernel(
    const u32* __restrict__ g1_in, const float* __restrict__ g1_W,
    const float* __restrict__ g1_bih, const float* __restrict__ g1_bhh,
    f16* __restrict__ g1_xg, int g1_t0, int g1_on,
    const float* __restrict__ g0_x, const float* __restrict__ g0_W,
    const float* __restrict__ g0_bih, const float* __restrict__ g0_bhh,
    f16* __restrict__ g0_xg, int g0_t0, int g0_on) {
  __shared__ uint4 wL[8][1024];  // gemm1 weight overflow (128 KiB), tid-indexed
  const int blk = blockIdx.x;
  const int tid = threadIdx.x;
  const int r0 = tid, r1 = tid + 512;

  if (blk < 256) {
    if (!g1_on) return;
    const int b = blk >> 1, tpart = blk & 1;
    uint4 w0r[24], w1r[24];
    {
      const float* p0 = g1_W + (size_t)r0 * NH;
      const float* p1 = g1_W + (size_t)r1 * NH;
#pragma unroll
      for (int k = 0; k < 32; ++k) {
        float4 a = *(const float4*)(p0 + 8 * k);
        float4 c = *(const float4*)(p0 + 8 * k + 4);
        uint4 v0 = uint4{pkh(a.x, a.y), pkh(a.z, a.w), pkh(c.x, c.y), pkh(c.z, c.w)};
        float4 d = *(const float4*)(p1 + 8 * k);
        float4 e = *(const float4*)(p1 + 8 * k + 4);
        uint4 v1 = uint4{pkh(d.x, d.y), pkh(d.z, d.w), pkh(e.x, e.y), pkh(e.z, e.w)};
        if (k < 24) { w0r[k] = v0; w1r[k] = v1; }
        else { wL[k - 24][r0] = v0; wL[k - 24][r1] = v1; }
      }
    }
    const float bs0 = g1_bih[r0] + g1_bhh[r0];
    const float bs1 = g1_bih[r1] + g1_bhh[r1];
    __syncthreads();
#pragma unroll 1
    for (int tl = 0; tl < 32; ++tl) {
      const int tloc = tpart * 32 + tl;
      const u32* ip = g1_in + ((size_t)b * NS + g1_t0 + tloc) * 128;
      float a0 = 0.f, a1 = 0.f;
#pragma unroll
      for (int k = 0; k < 32; ++k) {
        uint4 xv = *(const uint4*)(ip + 4 * k);
        uint4 wa = (k < 24) ? w0r[k] : wL[k - 24][r0];
        uint4 wb = (k < 24) ? w1r[k] : wL[k - 24][r1];
        a0 = fdot2(wa.x, xv.x, a0); a0 = fdot2(wa.y, xv.y, a0);
        a0 = fdot2(wa.z, xv.z, a0); a0 = fdot2(wa.w, xv.w, a0);
        a1 = fdot2(wb.x, xv.x, a1); a1 = fdot2(wb.y, xv.y, a1);
        a1 = fdot2(wb.z, xv.z, a1); a1 = fdot2(wb.w, xv.w, a1);
      }
      f16* op = g1_xg + ((size_t)b * CH + tloc) * 1024;
      op[r0] = (f16)(a0 + bs0);
      op[r1] = (f16)(a1 + bs1);
    }
  } else {
    if (!g0_on) return;
    const int idx = blk - 256;
    const int b = idx >> 1, tpart = idx & 1;
    uint4 w0r[16], w1r[16];
    {
      const float* p0 = g0_W + (size_t)r0 * NV;
      const float* p1 = g0_W + (size_t)r1 * NV;
#pragma unroll
      for (int k = 0; k < 16; ++k) {
        float4 a = *(const float4*)(p0 + 8 * k);
        float4 c = *(const float4*)(p0 + 8 * k + 4);
        w0r[k] = uint4{pkh(a.x, a.y), pkh(a.z, a.w), pkh(c.x, c.y), pkh(c.z, c.w)};
        float4 d = *(const float4*)(p1 + 8 * k);
        float4 e = *(const float4*)(p1 + 8 * k + 4);
        w1r[k] = uint4{pkh(d.x, d.y), pkh(d.z, d.w), pkh(e.x, e.y), pkh(e.z, e.w)};
      }
    }
    const float bs0 = g0_bih[r0] + g0_bhh[r0];
    const float bs1 = g0_bih[r1] + g0_bhh[r1];
#pragma unroll 1
    for (int tl = 0; tl < 32; ++tl) {
      const int tloc = tpart * 32 + tl;
      const float* xp = g0_x + ((size_t)b * NS + g0_t0 + tloc) * NV;
      float a0 = 0.f, a1 = 0.f;
#pragma unroll
      for (int k = 0; k < 16; ++k) {
        float4 xa = *(const float4*)(xp + 8 * k);
        float4 xb = *(const float4*)(xp + 8 * k + 4);
        const u32 j0 = pkz(xa.x, xa.y), j1 = pkz(xa.z, xa.w);
        const u32 j2 = pkz(xb.x, xb.y), j3 = pkz(xb.z, xb.w);
        a0 = fdot2(w0r[k].x, j0, a0); a0 = fdot2(w0r[k].y, j1, a0);
        a0 = fdot2(w0r[k].z, j2, a0); a0 = fdot2(w0r[k].w, j3, a0);
        a1 = fdot2(w1r[k].x, j0, a1); a1 = fdot2(w1r[k].y, j1, a1);
        a1 = fdot2(w1r[k].z, j2, a1); a1 = fdot2(w1r[k].w, j3, a1);
      }
      f16* op = g0_xg + ((size_t)b * CH + tloc) * 1024;
      op[r0] = (f16)(a0 + bs0);
      op[r1] = (f16)(a1 + bs1);
    }
  }
}

// ---------------------------------------------------------------------------
// scan pair. Two changes vs round 8 (202us, VGPR=128, 8.65M bank conflicts):
//  1. waves_per_eu(2,2) pin: LDS caps at 1 WG/CU = 2 waves/EU, so round-8's
//     128-VGPR choice spilled ~100 regs for occupancy it could never get.
//     Pin -> ~230 VGPR granted -> no per-step L2 scratch reloads.
//     (Round-7 scan ran this pin: inferred ~130us vs 202us same body.)
//  2. wL0/wL1 indexed by tid (contiguous 16B/lane, conflict-free) instead of
//     wL[k][r0] with r0=(tid&1)*256+(tid>>1), whose lane pairs alias the same
//     banks 8-way (the 8.65M SQ_LDS_BANK_CONFLICT, ~530 stall cyc/CU/step).
// ---------------------------------------------------------------------------
__global__ __attribute__((amdgpu_flat_work_group_size(512, 512),
                          amdgpu_waves_per_eu(2, 2)))
void scan_pair_kernel(
    const f16* __restrict__ xgA, const float* __restrict__ WhhA,
    u32* __restrict__ slotsA, u32* __restrict__ hseedA, float* __restrict__ carryA,
    int t0A, int firstA, int onA,
    const f16* __restrict__ xgB, const float* __restrict__ WhhB,
    u32* __restrict__ slotsB, u32* __restrict__ hseedB, float* __restrict__ carryB,
    int t0B, int firstB, int onB) {
  __shared__ uint4 wL0[8][512];                 // r0-row overflow, tid-indexed
  __shared__ uint4 wL1[8][512];                 // r1-row overflow, tid-indexed
  __shared__ __align__(16) u32 hbuf[2][128];    // h as 256 f16, double-buffered

  const int blk = blockIdx.x;
  const int tid = threadIdx.x;
  const f16* xg; const float* Whh; u32* slots; u32* hseed; float* carry;
  int t0, first, b;
  if (blk < 128) {
    if (!onA) return;
    b = blk; xg = xgA; Whh = WhhA; slots = slotsA; hseed = hseedA; carry = carryA;
    t0 = t0A; first = firstA;
  } else {
    if (!onB) return;
    b = blk - 128; xg = xgB; Whh = WhhB; slots = slotsB; hseed = hseedB; carry = carryB;
    t0 = t0B; first = firstB;
  }
  const int p = tid & 1;
  const int u = tid >> 1;
  const int lane = tid & 63;
  const int r0 = p * 256 + u;   // gate i (p=0) / f (p=1)
  const int r1 = r0 + 512;      // gate g (p=0) / o (p=1)

  uint4 w0r[24], w1r[24];
  {
    const float* p0 = Whh + (size_t)r0 * NH;
    const float* p1 = Whh + (size_t)r1 * NH;
#pragma unroll
    for (int k = 0; k < 32; ++k) {
      float4 a = *(const float4*)(p0 + 8 * k);
      float4 c2 = *(const float4*)(p0 + 8 * k + 4);
      uint4 v0 = uint4{pkh(a.x, a.y), pkh(a.z, a.w), pkh(c2.x, c2.y), pkh(c2.z, c2.w)};
      float4 d = *(const float4*)(p1 + 8 * k);
      float4 e = *(const float4*)(p1 + 8 * k + 4);
      uint4 v1 = uint4{pkh(d.x, d.y), pkh(d.z, d.w), pkh(e.x, e.y), pkh(e.z, e.w)};
      if (k < 24) { w0r[k] = v0; w1r[k] = v1; }
      else { wL0[k - 24][tid] = v0; wL1[k - 24][tid] = v1; }
    }
  }
  float c;
  if (first) {
    if (tid < 128) hbuf[0][tid] = 0u;
    c = 0.f;
  } else {
    if (tid < 128) hbuf[0][tid] = hseed[b * 128 + tid];
    c = carry[b * 256 + u];
  }
  __syncthreads();

#pragma unroll 1
  for (int tl = 0; tl < CH; ++tl) {
    const int cur = tl & 1, nxt = cur ^ 1;
    const f16* xp = xg + ((size_t)b * CH + tl) * 1024;
    const float xa = (float)xp[r0];
    const float xb = (float)xp[r1];

    // lane l holds h u32s {2l, 2l+1}; broadcast via readlane -> SGPR src
    const uint2 hv = *(const uint2*)&hbuf[cur][2 * lane];

    float a0 = 0.f, a1 = 0.f;
#pragma unroll
    for (int k = 0; k < 32; ++k) {
      const u32 s0 = (u32)__builtin_amdgcn_readlane((int)hv.x, 2 * k);
      const u32 s1 = (u32)__builtin_amdgcn_readlane((int)hv.y, 2 * k);
      const u32 s2 = (u32)__builtin_amdgcn_readlane((int)hv.x, 2 * k + 1);
      const u32 s3 = (u32)__builtin_amdgcn_readlane((int)hv.y, 2 * k + 1);
      const uint4 wa = (k < 24) ? w0r[k] : wL0[k - 24][tid];
      const uint4 wb = (k < 24) ? w1r[k] : wL1[k - 24][tid];
      a0 = fdot2(wa.x, s0, a0); a0 = fdot2(wa.y, s1, a0);
      a0 = fdot2(wa.z, s2, a0); a0 = fdot2(wa.w, s3, a0);
      a1 = fdot2(wb.x, s0, a1); a1 = fdot2(wb.y, s1, a1);
      a1 = fdot2(wb.z, s2, a1); a1 = fdot2(wb.w, s3, a1);
    }
    a0 += xa; a1 += xb;
    const float px0 = __shfl_xor(a0, 1);   // partner lane: other two gates
    const float px1 = __shfl_xor(a1, 1);
    const float ai = p ? px0 : a0;
    const float ag = p ? px1 : a1;
    const float af = p ? a0 : px0;
    const float ao = p ? a1 : px1;
    const float gi = sigm(ai), gg = tanh_(ag), gf = sigm(af), go = sigm(ao);
    c = gf * c + gi * gg;                  // redundant in both lanes (same value)
    const float h = go * tanh_(c);
    if (p == 0) {
      ((f16*)hbuf[nxt])[u] = (f16)h;
      ((f16*)(slots + ((size_t)b * NS + t0 + tl) * 128))[u] = (f16)h;
    }
    __syncthreads();  // single barrier: h(t) visible for next step
  }
  if (tid < 128) hseed[b * 128 + tid] = hbuf[0][tid];  // CH even -> final in [0]
  if (p == 0) carry[b * 256 + u] = c;
}

// ---------------------------------------------------------------------------
// outproj: out = Wout·h1 + b, IN PLACE over d_out slots. Unchanged (validated).
// ---------------------------------------------------------------------------
__global__ __launch_bounds__(1024) void outproj_kernel(
    const float* __restrict__ Wout, const float* __restrict__ bout,
    u32* __restrict__ io) {
  const int bs = blockIdx.x;  // 2048 blocks
  const int b = bs >> 4;
  const int t0 = (bs & 15) * 64;
  const int tid = threadIdx.x;
  const int p = tid & 7;
  const int vq = tid >> 3;

  __shared__ u32 h1L[64 * 128];
  __shared__ float outL[64 * 128];

  const u32* src = io + ((size_t)b * NS + t0) * 128;
  uint4 s0 = *(const uint4*)(src + (size_t)tid * 8);
  uint4 s1 = *(const uint4*)(src + (size_t)tid * 8 + 4);

  u32 wo[16];
  const float* pw = Wout + (size_t)vq * NH + p * 32;
#pragma unroll
  for (int k = 0; k < 8; ++k) {
    float4 w4 = *(const float4*)(pw + 4 * k);
    wo[2 * k] = pkh(w4.x, w4.y); wo[2 * k + 1] = pkh(w4.z, w4.w);
  }
  const float bo = bout[vq];

  *(uint4*)&h1L[tid * 8] = s0;
  *(uint4*)&h1L[tid * 8 + 4] = s1;
  __syncthreads();

#pragma unroll 4
  for (int s = 0; s < 64; ++s) {
    float oa = 0.f;
#pragma unroll
    for (int q = 0; q < 4; ++q) {
      uint4 hq = *(const uint4*)&h1L[s * 128 + p * 16 + 4 * q];
      u32 hw[4] = {hq.x, hq.y, hq.z, hq.w};
#pragma unroll
      for (int j = 0; j < 4; ++j) oa = fdot2(wo[4 * q + j], hw[j], oa);
    }
    oa += __shfl_xor(oa, 1);
    oa += __shfl_xor(oa, 2);
    oa += __shfl_xor(oa, 4);
    if (p == 0) outL[s * 128 + vq] = oa + bo;
  }
  __syncthreads();

  float* df = (float*)(io + ((size_t)b * NS + t0) * 128);
  *(float4*)(df + (size_t)tid * 8) = *(float4*)&outL[tid * 8];
  *(float4*)(df + (size_t)tid * 8 + 4) = *(float4*)&outL[tid * 8 + 4];
}

extern "C" void kernel_launch(void* const* d_in, const int* in_sizes, int n_in,
                              void* d_out, int out_size, void* d_ws, size_t ws_size,
                              hipStream_t stream) {
  const float* x    = (const float*)d_in[0];
  const float* Wih0 = (const float*)d_in[1];
  const float* Whh0 = (const float*)d_in[2];
  const float* bih0 = (const float*)d_in[3];
  const float* bhh0 = (const float*)d_in[4];
  const float* Wih1 = (const float*)d_in[5];
  const float* Whh1 = (const float*)d_in[6];
  const float* bih1 = (const float*)d_in[7];
  const float* bhh1 = (const float*)d_in[8];
  const float* Wout = (const float*)d_in[9];
  const float* bout = (const float*)d_in[10];

  // ws (<= 32.5 MiB): xg0 | xg1 | hseed0 | hseed1 | carry0 | carry1
  f16* xg0 = (f16*)d_ws;
  f16* xg1 = (f16*)((char*)d_ws + (16u << 20));
  u32* hseed0 = (u32*)((char*)d_ws + (32u << 20));
  u32* hseed1 = (u32*)((char*)d_ws + (32u << 20) + (64u << 10));
  float* carry0 = (float*)((char*)d_ws + (32u << 20) + (128u << 10));
  float* carry1 = (float*)((char*)d_ws + (32u << 20) + (256u << 10));
  u32* slots = (u32*)d_out;  // h0 -> h1 -> f32 out, in place per chunk row

  // prologue: gemm0(0); scan0(0)
  gemm_pair_kernel<<<512, 512, 0, stream>>>(
      nullptr, nullptr, nullptr, nullptr, nullptr, 0, 0,
      x, Wih0, bih0, bhh0, xg0, 0, 1);
  scan_pair_kernel<<<256, 512, 0, stream>>>(
      nullptr, nullptr, nullptr, nullptr, nullptr, 0, 0, 0,
      xg0, Whh0, slots, hseed0, carry0, 0, 1, 1);

  // pipeline: A(s) = gemm1(s) || gemm0(s+1);  B(s) = scan1(s) || scan0(s+1)
  for (int s = 0; s < NCH; ++s) {
    const int g0on = (s + 1 < NCH);
    gemm_pair_kernel<<<512, 512, 0, stream>>>(
        slots, Wih1, bih1, bhh1, xg1, s * CH, 1,
        x, Wih0, bih0, bhh0, xg0, (s + 1) * CH, g0on);
    scan_pair_kernel<<<256, 512, 0, stream>>>(
        xg1, Whh1, slots, hseed1, carry1, s * CH, (s == 0) ? 1 : 0, 1,
        xg0, Whh0, slots, hseed0, carry0, (s + 1) * CH, 0, g0on);
  }
  outproj_kernel<<<2048, 1024, 0, stream>>>(Wout, bout, slots);
}

// Round 10
// 5211.938 us; speedup vs baseline: 1.1436x; 1.1436x over previous
//
#include <hip/hip_runtime.h>
#include <cstdint>

#define NB 128   // batch
#define NS 1024  // seq len
#define NV 128   // input dim
#define NH 256   // hidden
#define CH 64    // chunk length
#define NCH (NS / CH)

typedef _Float16 f16;
typedef _Float16 h2 __attribute__((ext_vector_type(2)));
typedef uint32_t u32;

static __device__ __forceinline__ float fdot2(u32 a, u32 b, float c) {
  return __builtin_amdgcn_fdot2(__builtin_bit_cast(h2, a),
                                __builtin_bit_cast(h2, b), c, false);
}
static __device__ __forceinline__ u32 pkh(float a, float b) {  // RTN (preload)
  union { h2 h; u32 u; } cv; cv.h = h2{(f16)a, (f16)b}; return cv.u;
}
static __device__ __forceinline__ u32 pkz(float a, float b) {  // RTZ (hot path)
  return __builtin_bit_cast(u32, __builtin_amdgcn_cvt_pkrtz(a, b));
}
static __device__ __forceinline__ float sigm(float x) { return 1.f / (1.f + __expf(-x)); }
static __device__ __forceinline__ float tanh_(float x) { return 1.f - 2.f / (__expf(2.f * x) + 1.f); }

// Pin a uint4's components into VGPRs via an opaque asm def: the register
// allocator CANNOT rematerialize an asm result, so the only choices are
// "keep resident" or scratch-spill (visible in WRITE_SIZE). This defeats the
// per-step reload+repack remat that r6-r9 showed (VALU 3.5x inflated,
// VGPR_Count stuck at 52-128 regardless of launch-bounds/waves_per_eu).
static __device__ __forceinline__ void pin4(uint4& v) {
  asm volatile("" : "+v"(v.x), "+v"(v.y), "+v"(v.z), "+v"(v.w));
}

// ---------------------------------------------------------------------------
// gemm1: xg1 = Wih1·h0(t) + biases. 256 blocks (b, tpart); 512 threads;
// thread owns rows tid, tid+512: 32 uint4/row = 24 pinned VGPR + 8 LDS.
// waves_per_eu(2,2): LDS 128KiB caps 1 WG/CU anyway -> 256-VGPR budget.
// ---------------------------------------------------------------------------
__global__ __attribute__((amdgpu_flat_work_group_size(512, 512),
                          amdgpu_waves_per_eu(2, 2)))
void gemm1_kernel(const u32* __restrict__ in, const float* __restrict__ W,
                  const float* __restrict__ bih, const float* __restrict__ bhh,
                  f16* __restrict__ xg, int t0) {
  __shared__ uint4 wL0[8][512];
  __shared__ uint4 wL1[8][512];
  const int blk = blockIdx.x;
  const int tid = threadIdx.x;
  const int r0 = tid, r1 = tid + 512;
  const int b = blk >> 1, tpart = blk & 1;

  uint4 w0r[24], w1r[24];
  {
    const float* p0 = W + (size_t)r0 * NH;
    const float* p1 = W + (size_t)r1 * NH;
#pragma unroll
    for (int k = 0; k < 32; ++k) {
      float4 a = *(const float4*)(p0 + 8 * k);
      float4 c = *(const float4*)(p0 + 8 * k + 4);
      uint4 v0 = uint4{pkh(a.x, a.y), pkh(a.z, a.w), pkh(c.x, c.y), pkh(c.z, c.w)};
      float4 d = *(const float4*)(p1 + 8 * k);
      float4 e = *(const float4*)(p1 + 8 * k + 4);
      uint4 v1 = uint4{pkh(d.x, d.y), pkh(d.z, d.w), pkh(e.x, e.y), pkh(e.z, e.w)};
      if (k < 24) { w0r[k] = v0; w1r[k] = v1; }
      else { wL0[k - 24][tid] = v0; wL1[k - 24][tid] = v1; }
    }
  }
#pragma unroll
  for (int k = 0; k < 24; ++k) { pin4(w0r[k]); pin4(w1r[k]); }
  const float bs0 = bih[r0] + bhh[r0];
  const float bs1 = bih[r1] + bhh[r1];
  __syncthreads();
#pragma unroll 1
  for (int tl = 0; tl < 32; ++tl) {
    const int tloc = tpart * 32 + tl;
    const u32* ip = in + ((size_t)b * NS + t0 + tloc) * 128;
    float a0 = 0.f, a1 = 0.f;
#pragma unroll
    for (int k = 0; k < 32; ++k) {
      uint4 xv = *(const uint4*)(ip + 4 * k);
      uint4 wa = (k < 24) ? w0r[k] : wL0[k - 24][tid];
      uint4 wb = (k < 24) ? w1r[k] : wL1[k - 24][tid];
      a0 = fdot2(wa.x, xv.x, a0); a0 = fdot2(wa.y, xv.y, a0);
      a0 = fdot2(wa.z, xv.z, a0); a0 = fdot2(wa.w, xv.w, a0);
      a1 = fdot2(wb.x, xv.x, a1); a1 = fdot2(wb.y, xv.y, a1);
      a1 = fdot2(wb.z, xv.z, a1); a1 = fdot2(wb.w, xv.w, a1);
    }
    f16* op = xg + ((size_t)b * CH + tloc) * 1024;
    op[r0] = (f16)(a0 + bs0);
    op[r1] = (f16)(a1 + bs1);
  }
}

// ---------------------------------------------------------------------------
// gemm0: xg0 = Wih0·x(t) + biases. 256 blocks; thread owns rows tid, tid+512:
// 16 uint4/row, all pinned in VGPRs (128 + working ~40 <= 256 budget). No LDS.
// ---------------------------------------------------------------------------
__global__ __attribute__((amdgpu_flat_work_group_size(512, 512),
                          amdgpu_waves_per_eu(2, 2)))
void gemm0_kernel(const float* __restrict__ x, const float* __restrict__ W,
                  const float* __restrict__ bih, const float* __restrict__ bhh,
                  f16* __restrict__ xg, int t0) {
  const int blk = blockIdx.x;
  const int tid = threadIdx.x;
  const int r0 = tid, r1 = tid + 512;
  const int b = blk >> 1, tpart = blk & 1;

  uint4 w0r[16], w1r[16];
  {
    const float* p0 = W + (size_t)r0 * NV;
    const float* p1 = W + (size_t)r1 * NV;
#pragma unroll
    for (int k = 0; k < 16; ++k) {
      float4 a = *(const float4*)(p0 + 8 * k);
      float4 c = *(const float4*)(p0 + 8 * k + 4);
      w0r[k] = uint4{pkh(a.x, a.y), pkh(a.z, a.w), pkh(c.x, c.y), pkh(c.z, c.w)};
      float4 d = *(const float4*)(p1 + 8 * k);
      float4 e = *(const float4*)(p1 + 8 * k + 4);
      w1r[k] = uint4{pkh(d.x, d.y), pkh(d.z, d.w), pkh(e.x, e.y), pkh(e.z, e.w)};
    }
  }
#pragma unroll
  for (int k = 0; k < 16; ++k) { pin4(w0r[k]); pin4(w1r[k]); }
  const float bs0 = bih[r0] + bhh[r0];
  const float bs1 = bih[r1] + bhh[r1];
#pragma unroll 1
  for (int tl = 0; tl < 32; ++tl) {
    const int tloc = tpart * 32 + tl;
    const float* xp = x + ((size_t)b * NS + t0 + tloc) * NV;
    float a0 = 0.f, a1 = 0.f;
#pragma unroll
    for (int k = 0; k < 16; ++k) {
      float4 xa = *(const float4*)(xp + 8 * k);
      float4 xb = *(const float4*)(xp + 8 * k + 4);
      const u32 j0 = pkz(xa.x, xa.y), j1 = pkz(xa.z, xa.w);
      const u32 j2 = pkz(xb.x, xb.y), j3 = pkz(xb.z, xb.w);
      a0 = fdot2(w0r[k].x, j0, a0); a0 = fdot2(w0r[k].y, j1, a0);
      a0 = fdot2(w0r[k].z, j2, a0); a0 = fdot2(w0r[k].w, j3, a0);
      a1 = fdot2(w1r[k].x, j0, a1); a1 = fdot2(w1r[k].y, j1, a1);
      a1 = fdot2(w1r[k].z, j2, a1); a1 = fdot2(w1r[k].w, j3, a1);
    }
    f16* op = xg + ((size_t)b * CH + tloc) * 1024;
    op[r0] = (f16)(a0 + bs0);
    op[r1] = (f16)(a1 + bs1);
  }
}

// ---------------------------------------------------------------------------
// scan pair (round-9 body + pinned weights). 256 blocks, 1 WG/CU.
//  blocks [0,128) = scan1 chunk s; [128,256) = scan0 chunk s+1.
// 512 threads: u=tid>>1, p=tid&1; rows r0=p*256+u (i/f), r1=r0+512 (g/o).
// 24 uint4/row pinned in VGPRs + 8 in LDS (tid-indexed, conflict-free).
// h(t-1): ds_read_b64 per lane -> v_readlane -> SGPR src of fdot2.
// One __shfl_xor(,1) partner-gate exchange; ONE barrier per step.
// ---------------------------------------------------------------------------
__global__ __attribute__((amdgpu_flat_work_group_size(512, 512),
                          amdgpu_waves_per_eu(2, 2)))
void scan_pair_kernel(
    const f16* __restrict__ xgA, const float* __restrict__ WhhA,
    u32* __restrict__ slotsA, u32* __restrict__ hseedA, float* __restrict__ carryA,
    int t0A, int firstA, int onA,
    const f16* __restrict__ xgB, const float* __restrict__ WhhB,
    u32* __restrict__ slotsB, u32* __restrict__ hseedB, float* __restrict__ carryB,
    int t0B, int firstB, int onB) {
  __shared__ uint4 wL0[8][512];                 // r0-row overflow, tid-indexed
  __shared__ uint4 wL1[8][512];                 // r1-row overflow, tid-indexed
  __shared__ __align__(16) u32 hbuf[2][128];    // h as 256 f16, double-buffered

  const int blk = blockIdx.x;
  const int tid = threadIdx.x;
  const f16* xg; const float* Whh; u32* slots; u32* hseed; float* carry;
  int t0, first, b;
  if (blk < 128) {
    if (!onA) return;
    b = blk; xg = xgA; Whh = WhhA; slots = slotsA; hseed = hseedA; carry = carryA;
    t0 = t0A; first = firstA;
  } else {
    if (!onB) return;
    b = blk - 128; xg = xgB; Whh = WhhB; slots = slotsB; hseed = hseedB; carry = carryB;
    t0 = t0B; first = firstB;
  }
  const int p = tid & 1;
  const int u = tid >> 1;
  const int lane = tid & 63;
  const int r0 = p * 256 + u;   // gate i (p=0) / f (p=1)
  const int r1 = r0 + 512;      // gate g (p=0) / o (p=1)

  uint4 w0r[24], w1r[24];
  {
    const float* p0 = Whh + (size_t)r0 * NH;
    const float* p1 = Whh + (size_t)r1 * NH;
#pragma unroll
    for (int k = 0; k < 32; ++k) {
      float4 a = *(const float4*)(p0 + 8 * k);
      float4 c2 = *(const float4*)(p0 + 8 * k + 4);
      uint4 v0 = uint4{pkh(a.x, a.y), pkh(a.z, a.w), pkh(c2.x, c2.y), pkh(c2.z, c2.w)};
      float4 d = *(const float4*)(p1 + 8 * k);
      float4 e = *(const float4*)(p1 + 8 * k + 4);
      uint4 v1 = uint4{pkh(d.x, d.y), pkh(d.z, d.w), pkh(e.x, e.y), pkh(e.z, e.w)};
      if (k < 24) { w0r[k] = v0; w1r[k] = v1; }
      else { wL0[k - 24][tid] = v0; wL1[k - 24][tid] = v1; }
    }
  }
#pragma unroll
  for (int k = 0; k < 24; ++k) { pin4(w0r[k]); pin4(w1r[k]); }
  float c;
  if (first) {
    if (tid < 128) hbuf[0][tid] = 0u;
    c = 0.f;
  } else {
    if (tid < 128) hbuf[0][tid] = hseed[b * 128 + tid];
    c = carry[b * 256 + u];
  }
  __syncthreads();

#pragma unroll 1
  for (int tl = 0; tl < CH; ++tl) {
    const int cur = tl & 1, nxt = cur ^ 1;
    const f16* xp = xg + ((size_t)b * CH + tl) * 1024;
    const float xa = (float)xp[r0];
    const float xb = (float)xp[r1];

    // lane l holds h u32s {2l, 2l+1}; broadcast via readlane -> SGPR src
    const uint2 hv = *(const uint2*)&hbuf[cur][2 * lane];

    float a0 = 0.f, a1 = 0.f;
#pragma unroll
    for (int k = 0; k < 32; ++k) {
      const u32 s0 = (u32)__builtin_amdgcn_readlane((int)hv.x, 2 * k);
      const u32 s1 = (u32)__builtin_amdgcn_readlane((int)hv.y, 2 * k);
      const u32 s2 = (u32)__builtin_amdgcn_readlane((int)hv.x, 2 * k + 1);
      const u32 s3 = (u32)__builtin_amdgcn_readlane((int)hv.y, 2 * k + 1);
      const uint4 wa = (k < 24) ? w0r[k] : wL0[k - 24][tid];
      const uint4 wb = (k < 24) ? w1r[k] : wL1[k - 24][tid];
      a0 = fdot2(wa.x, s0, a0); a0 = fdot2(wa.y, s1, a0);
      a0 = fdot2(wa.z, s2, a0); a0 = fdot2(wa.w, s3, a0);
      a1 = fdot2(wb.x, s0, a1); a1 = fdot2(wb.y, s1, a1);
      a1 = fdot2(wb.z, s2, a1); a1 = fdot2(wb.w, s3, a1);
    }
    a0 += xa; a1 += xb;
    const float px0 = __shfl_xor(a0, 1);   // partner lane: other two gates
    const float px1 = __shfl_xor(a1, 1);
    const float ai = p ? px0 : a0;
    const float ag = p ? px1 : a1;
    const float af = p ? a0 : px0;
    const float ao = p ? a1 : px1;
    const float gi = sigm(ai), gg = tanh_(ag), gf = sigm(af), go = sigm(ao);
    c = gf * c + gi * gg;                  // redundant in both lanes (same value)
    const float h = go * tanh_(c);
    if (p == 0) {
      ((f16*)hbuf[nxt])[u] = (f16)h;
      ((f16*)(slots + ((size_t)b * NS + t0 + tl) * 128))[u] = (f16)h;
    }
    __syncthreads();  // single barrier: h(t) visible for next step
  }
  if (tid < 128) hseed[b * 128 + tid] = hbuf[0][tid];  // CH even -> final in [0]
  if (p == 0) carry[b * 256 + u] = c;
}

// ---------------------------------------------------------------------------
// outproj: out = Wout·h1 + b, IN PLACE over d_out slots. Unchanged (validated).
// ---------------------------------------------------------------------------
__global__ __launch_bounds__(1024) void outproj_kernel(
    const float* __restrict__ Wout, const float* __restrict__ bout,
    u32* __restrict__ io) {
  const int bs = blockIdx.x;  // 2048 blocks
  const int b = bs >> 4;
  const int t0 = (bs & 15) * 64;
  const int tid = threadIdx.x;
  const int p = tid & 7;
  const int vq = tid >> 3;

  __shared__ u32 h1L[64 * 128];
  __shared__ float outL[64 * 128];

  const u32* src = io + ((size_t)b * NS + t0) * 128;
  uint4 s0 = *(const uint4*)(src + (size_t)tid * 8);
  uint4 s1 = *(const uint4*)(src + (size_t)tid * 8 + 4);

  u32 wo[16];
  const float* pw = Wout + (size_t)vq * NH + p * 32;
#pragma unroll
  for (int k = 0; k < 8; ++k) {
    float4 w4 = *(const float4*)(pw + 4 * k);
    wo[2 * k] = pkh(w4.x, w4.y); wo[2 * k + 1] = pkh(w4.z, w4.w);
  }
  const float bo = bout[vq];

  *(uint4*)&h1L[tid * 8] = s0;
  *(uint4*)&h1L[tid * 8 + 4] = s1;
  __syncthreads();

#pragma unroll 4
  for (int s = 0; s < 64; ++s) {
    float oa = 0.f;
#pragma unroll
    for (int q = 0; q < 4; ++q) {
      uint4 hq = *(const uint4*)&h1L[s * 128 + p * 16 + 4 * q];
      u32 hw[4] = {hq.x, hq.y, hq.z, hq.w};
#pragma unroll
      for (int j = 0; j < 4; ++j) oa = fdot2(wo[4 * q + j], hw[j], oa);
    }
    oa += __shfl_xor(oa, 1);
    oa += __shfl_xor(oa, 2);
    oa += __shfl_xor(oa, 4);
    if (p == 0) outL[s * 128 + vq] = oa + bo;
  }
  __syncthreads();

  float* df = (float*)(io + ((size_t)b * NS + t0) * 128);
  *(float4*)(df + (size_t)tid * 8) = *(float4*)&outL[tid * 8];
  *(float4*)(df + (size_t)tid * 8 + 4) = *(float4*)&outL[tid * 8 + 4];
}

extern "C" void kernel_launch(void* const* d_in, const int* in_sizes, int n_in,
                              void* d_out, int out_size, void* d_ws, size_t ws_size,
                              hipStream_t stream) {
  const float* x    = (const float*)d_in[0];
  const float* Wih0 = (const float*)d_in[1];
  const float* Whh0 = (const float*)d_in[2];
  const float* bih0 = (const float*)d_in[3];
  const float* bhh0 = (const float*)d_in[4];
  const float* Wih1 = (const float*)d_in[5];
  const float* Whh1 = (const float*)d_in[6];
  const float* bih1 = (const float*)d_in[7];
  const float* bhh1 = (const float*)d_in[8];
  const float* Wout = (const float*)d_in[9];
  const float* bout = (const float*)d_in[10];

  // ws (<= 32.5 MiB): xg0 | xg1 | hseed0 | hseed1 | carry0 | carry1
  f16* xg0 = (f16*)d_ws;
  f16* xg1 = (f16*)((char*)d_ws + (16u << 20));
  u32* hseed0 = (u32*)((char*)d_ws + (32u << 20));
  u32* hseed1 = (u32*)((char*)d_ws + (32u << 20) + (64u << 10));
  float* carry0 = (float*)((char*)d_ws + (32u << 20) + (128u << 10));
  float* carry1 = (float*)((char*)d_ws + (32u << 20) + (256u << 10));
  u32* slots = (u32*)d_out;  // h0 -> h1 -> f32 out, in place per chunk row

  // prologue: gemm0(0); scan0(0)
  gemm0_kernel<<<256, 512, 0, stream>>>(x, Wih0, bih0, bhh0, xg0, 0);
  scan_pair_kernel<<<256, 512, 0, stream>>>(
      nullptr, nullptr, nullptr, nullptr, nullptr, 0, 0, 0,
      xg0, Whh0, slots, hseed0, carry0, 0, 1, 1);

  // pipeline: gemm1(s); gemm0(s+1); then scan1(s) || scan0(s+1)
  for (int s = 0; s < NCH; ++s) {
    const int g0on = (s + 1 < NCH);
    gemm1_kernel<<<256, 512, 0, stream>>>(slots, Wih1, bih1, bhh1, xg1, s * CH);
    if (g0on)
      gemm0_kernel<<<256, 512, 0, stream>>>(x, Wih0, bih0, bhh0, xg0, (s + 1) * CH);
    scan_pair_kernel<<<256, 512, 0, stream>>>(
        xg1, Whh1, slots, hseed1, carry1, s * CH, (s == 0) ? 1 : 0, 1,
        xg0, Whh0, slots, hseed0, carry0, (s + 1) * CH, 0, g0on);
  }
  outproj_kernel<<<2048, 1024, 0, stream>>>(Wout, bout, slots);
}

// Round 11
// 4917.043 us; speedup vs baseline: 1.2122x; 1.0600x over previous
//
#include <hip/hip_runtime.h>
#include <cstdint>

#define NB 128   // batch
#define NS 1024  // seq len
#define NV 128   // input dim
#define NH 256   // hidden
#define CH 64    // chunk length
#define NCH (NS / CH)

typedef _Float16 f16;
typedef _Float16 h2 __attribute__((ext_vector_type(2)));
typedef uint32_t u32;

static __device__ __forceinline__ float fdot2(u32 a, u32 b, float c) {
  return __builtin_amdgcn_fdot2(__builtin_bit_cast(h2, a),
                                __builtin_bit_cast(h2, b), c, false);
}
static __device__ __forceinline__ u32 pkh(float a, float b) {  // RTN (preload)
  union { h2 h; u32 u; } cv; cv.h = h2{(f16)a, (f16)b}; return cv.u;
}
static __device__ __forceinline__ u32 pkz(float a, float b) {  // RTZ (hot path)
  return __builtin_bit_cast(u32, __builtin_amdgcn_cvt_pkrtz(a, b));
}
static __device__ __forceinline__ float sigm(float x) { return 1.f / (1.f + __expf(-x)); }
static __device__ __forceinline__ float tanh_(float x) { return 1.f - 2.f / (__expf(2.f * x) + 1.f); }

// Opaque asm def: allocator cannot rematerialize -> weight packs stay resident
// (or at worst AGPR-resident; never re-loaded+re-packed from L2 per step).
static __device__ __forceinline__ void pin4(uint4& v) {
  asm volatile("" : "+v"(v.x), "+v"(v.y), "+v"(v.z), "+v"(v.w));
}

// ---------------------------------------------------------------------------
// gemm pair, one launch (512 blocks; each fills chip in 2 rounds @1 blk/CU).
//  blocks [0,256):  gemm1(s): xg1 = Wih1·h0(t)+biases. Thread owns rows tid,
//     tid+512: 32 uint4/row = 24 pinned VGPR + 8 LDS (tid-indexed).
//  blocks [256,512): gemm0(s+1): xg0 = Wih0·x(t)+biases. 16 uint4/row pinned.
// ---------------------------------------------------------------------------
__global__ __attribute__((amdgpu_flat_work_group_size(512, 512),
                          amdgpu_waves_per_eu(2, 2)))
void gemm_pair_kernel(
    const u32* __restrict__ g1_in, const float* __restrict__ g1_W,
    const float* __restrict__ g1_bih, const float* __restrict__ g1_bhh,
    f16* __restrict__ g1_xg, int g1_t0, int g1_on,
    const float* __restrict__ g0_x, const float* __restrict__ g0_W,
    const float* __restrict__ g0_bih, const float* __restrict__ g0_bhh,
    f16* __restrict__ g0_xg, int g0_t0, int g0_on) {
  __shared__ uint4 wL0[8][512];
  __shared__ uint4 wL1[8][512];
  const int blk = blockIdx.x;
  const int tid = threadIdx.x;
  const int r0 = tid, r1 = tid + 512;

  if (blk < 256) {
    if (!g1_on) return;
    const int b = blk >> 1, tpart = blk & 1;
    uint4 w0r[24], w1r[24];
    {
      const float* p0 = g1_W + (size_t)r0 * NH;
      const float* p1 = g1_W + (size_t)r1 * NH;
#pragma unroll
      for (int k = 0; k < 32; ++k) {
        float4 a = *(const float4*)(p0 + 8 * k);
        float4 c = *(const float4*)(p0 + 8 * k + 4);
        uint4 v0 = uint4{pkh(a.x, a.y), pkh(a.z, a.w), pkh(c.x, c.y), pkh(c.z, c.w)};
        float4 d = *(const float4*)(p1 + 8 * k);
        float4 e = *(const float4*)(p1 + 8 * k + 4);
        uint4 v1 = uint4{pkh(d.x, d.y), pkh(d.z, d.w), pkh(e.x, e.y), pkh(e.z, e.w)};
        if (k < 24) { w0r[k] = v0; w1r[k] = v1; }
        else { wL0[k - 24][tid] = v0; wL1[k - 24][tid] = v1; }
      }
    }
#pragma unroll
    for (int k = 0; k < 24; ++k) { pin4(w0r[k]); pin4(w1r[k]); }
    const float bs0 = g1_bih[r0] + g1_bhh[r0];
    const float bs1 = g1_bih[r1] + g1_bhh[r1];
    __syncthreads();
#pragma unroll 1
    for (int tl = 0; tl < 32; ++tl) {
      const int tloc = tpart * 32 + tl;
      const u32* ip = g1_in + ((size_t)b * NS + g1_t0 + tloc) * 128;
      float a0 = 0.f, a1 = 0.f;
#pragma unroll
      for (int k = 0; k < 32; ++k) {
        uint4 xv = *(const uint4*)(ip + 4 * k);
        uint4 wa = (k < 24) ? w0r[k] : wL0[k - 24][tid];
        uint4 wb = (k < 24) ? w1r[k] : wL1[k - 24][tid];
        a0 = fdot2(wa.x, xv.x, a0); a0 = fdot2(wa.y, xv.y, a0);
        a0 = fdot2(wa.z, xv.z, a0); a0 = fdot2(wa.w, xv.w, a0);
        a1 = fdot2(wb.x, xv.x, a1); a1 = fdot2(wb.y, xv.y, a1);
        a1 = fdot2(wb.z, xv.z, a1); a1 = fdot2(wb.w, xv.w, a1);
      }
      f16* op = g1_xg + ((size_t)b * CH + tloc) * 1024;
      op[r0] = (f16)(a0 + bs0);
      op[r1] = (f16)(a1 + bs1);
    }
  } else {
    if (!g0_on) return;
    const int idx = blk - 256;
    const int b = idx >> 1, tpart = idx & 1;
    uint4 w0r[16], w1r[16];
    {
      const float* p0 = g0_W + (size_t)r0 * NV;
      const float* p1 = g0_W + (size_t)r1 * NV;
#pragma unroll
      for (int k = 0; k < 16; ++k) {
        float4 a = *(const float4*)(p0 + 8 * k);
        float4 c = *(const float4*)(p0 + 8 * k + 4);
        w0r[k] = uint4{pkh(a.x, a.y), pkh(a.z, a.w), pkh(c.x, c.y), pkh(c.z, c.w)};
        float4 d = *(const float4*)(p1 + 8 * k);
        float4 e = *(const float4*)(p1 + 8 * k + 4);
        w1r[k] = uint4{pkh(d.x, d.y), pkh(d.z, d.w), pkh(e.x, e.y), pkh(e.z, e.w)};
      }
    }
#pragma unroll
    for (int k = 0; k < 16; ++k) { pin4(w0r[k]); pin4(w1r[k]); }
    const float bs0 = g0_bih[r0] + g0_bhh[r0];
    const float bs1 = g0_bih[r1] + g0_bhh[r1];
#pragma unroll 1
    for (int tl = 0; tl < 32; ++tl) {
      const int tloc = tpart * 32 + tl;
      const float* xp = g0_x + ((size_t)b * NS + g0_t0 + tloc) * NV;
      float a0 = 0.f, a1 = 0.f;
#pragma unroll
      for (int k = 0; k < 16; ++k) {
        float4 xa = *(const float4*)(xp + 8 * k);
        float4 xb = *(const float4*)(xp + 8 * k + 4);
        const u32 j0 = pkz(xa.x, xa.y), j1 = pkz(xa.z, xa.w);
        const u32 j2 = pkz(xb.x, xb.y), j3 = pkz(xb.z, xb.w);
        a0 = fdot2(w0r[k].x, j0, a0); a0 = fdot2(w0r[k].y, j1, a0);
        a0 = fdot2(w0r[k].z, j2, a0); a0 = fdot2(w0r[k].w, j3, a0);
        a1 = fdot2(w1r[k].x, j0, a1); a1 = fdot2(w1r[k].y, j1, a1);
        a1 = fdot2(w1r[k].z, j2, a1); a1 = fdot2(w1r[k].w, j3, a1);
      }
      f16* op = g0_xg + ((size_t)b * CH + tloc) * 1024;
      op[r0] = (f16)(a0 + bs0);
      op[r1] = (f16)(a1 + bs1);
    }
  }
}

// ---------------------------------------------------------------------------
// scan pair. Inner loop reverted to the r6-proven form: h(t-1) distributed by
// UNIFORM-address ds_read_b128 broadcast (DS pipe, parallel to VALU) instead
// of readlane chains (VALU-serial; r8-r10 = 169-208us vs r6 ~112us inferred).
// wL0/wL1 tid-indexed (conflict-free, r9). pin4 keeps weight packs resident.
//  blocks [0,128) = scan1 chunk s; [128,256) = scan0 chunk s+1. 1 WG/CU.
// ---------------------------------------------------------------------------
__global__ __attribute__((amdgpu_flat_work_group_size(512, 512),
                          amdgpu_waves_per_eu(2, 2)))
void scan_pair_kernel(
    const f16* __restrict__ xgA, const float* __restrict__ WhhA,
    u32* __restrict__ slotsA, u32* __restrict__ hseedA, float* __restrict__ carryA,
    int t0A, int firstA, int onA,
    const f16* __restrict__ xgB, const float* __restrict__ WhhB,
    u32* __restrict__ slotsB, u32* __restrict__ hseedB, float* __restrict__ carryB,
    int t0B, int firstB, int onB) {
  __shared__ uint4 wL0[8][512];                 // r0-row overflow, tid-indexed
  __shared__ uint4 wL1[8][512];                 // r1-row overflow, tid-indexed
  __shared__ __align__(16) u32 hbuf[2][128];    // h as 256 f16, double-buffered

  const int blk = blockIdx.x;
  const int tid = threadIdx.x;
  const f16* xg; const float* Whh; u32* slots; u32* hseed; float* carry;
  int t0, first, b;
  if (blk < 128) {
    if (!onA) return;
    b = blk; xg = xgA; Whh = WhhA; slots = slotsA; hseed = hseedA; carry = carryA;
    t0 = t0A; first = firstA;
  } else {
    if (!onB) return;
    b = blk - 128; xg = xgB; Whh = WhhB; slots = slotsB; hseed = hseedB; carry = carryB;
    t0 = t0B; first = firstB;
  }
  const int p = tid & 1;
  const int u = tid >> 1;
  const int r0 = p * 256 + u;   // gate i (p=0) / f (p=1)
  const int r1 = r0 + 512;      // gate g (p=0) / o (p=1)

  uint4 w0r[24], w1r[24];
  {
    const float* p0 = Whh + (size_t)r0 * NH;
    const float* p1 = Whh + (size_t)r1 * NH;
#pragma unroll
    for (int k = 0; k < 32; ++k) {
      float4 a = *(const float4*)(p0 + 8 * k);
      float4 c2 = *(const float4*)(p0 + 8 * k + 4);
      uint4 v0 = uint4{pkh(a.x, a.y), pkh(a.z, a.w), pkh(c2.x, c2.y), pkh(c2.z, c2.w)};
      float4 d = *(const float4*)(p1 + 8 * k);
      float4 e = *(const float4*)(p1 + 8 * k + 4);
      uint4 v1 = uint4{pkh(d.x, d.y), pkh(d.z, d.w), pkh(e.x, e.y), pkh(e.z, e.w)};
      if (k < 24) { w0r[k] = v0; w1r[k] = v1; }
      else { wL0[k - 24][tid] = v0; wL1[k - 24][tid] = v1; }
    }
  }
#pragma unroll
  for (int k = 0; k < 24; ++k) { pin4(w0r[k]); pin4(w1r[k]); }
  float c;
  if (first) {
    if (tid < 128) hbuf[0][tid] = 0u;
    c = 0.f;
  } else {
    if (tid < 128) hbuf[0][tid] = hseed[b * 128 + tid];
    c = carry[b * 256 + u];
  }
  __syncthreads();

#pragma unroll 1
  for (int tl = 0; tl < CH; ++tl) {
    const int cur = tl & 1, nxt = cur ^ 1;
    const f16* xp = xg + ((size_t)b * CH + tl) * 1024;
    const float xa = (float)xp[r0];
    const float xb = (float)xp[r1];

    float a0 = 0.f, a1 = 0.f;
#pragma unroll
    for (int k = 0; k < 32; ++k) {
      uint4 hk = *(const uint4*)&hbuf[cur][4 * k];  // uniform addr -> broadcast
      const uint4 wa = (k < 24) ? w0r[k] : wL0[k - 24][tid];
      const uint4 wb = (k < 24) ? w1r[k] : wL1[k - 24][tid];
      a0 = fdot2(wa.x, hk.x, a0); a0 = fdot2(wa.y, hk.y, a0);
      a0 = fdot2(wa.z, hk.z, a0); a0 = fdot2(wa.w, hk.w, a0);
      a1 = fdot2(wb.x, hk.x, a1); a1 = fdot2(wb.y, hk.y, a1);
      a1 = fdot2(wb.z, hk.z, a1); a1 = fdot2(wb.w, hk.w, a1);
    }
    a0 += xa; a1 += xb;
    const float px0 = __shfl_xor(a0, 1);   // partner lane: other two gates
    const float px1 = __shfl_xor(a1, 1);
    const float ai = p ? px0 : a0;
    const float ag = p ? px1 : a1;
    const float af = p ? a0 : px0;
    const float ao = p ? a1 : px1;
    const float gi = sigm(ai), gg = tanh_(ag), gf = sigm(af), go = sigm(ao);
    c = gf * c + gi * gg;                  // redundant in both lanes (same value)
    const float h = go * tanh_(c);
    if (p == 0) {
      ((f16*)hbuf[nxt])[u] = (f16)h;
      ((f16*)(slots + ((size_t)b * NS + t0 + tl) * 128))[u] = (f16)h;
    }
    __syncthreads();  // single barrier: h(t) visible for next step
  }
  if (tid < 128) hseed[b * 128 + tid] = hbuf[0][tid];  // CH even -> final in [0]
  if (p == 0) carry[b * 256 + u] = c;
}

// ---------------------------------------------------------------------------
// outproj: out = Wout·h1 + b, IN PLACE over d_out slots. NEW: fine-grained
// LDS padding (phys col = col + 4*(col>>5), row stride 140) removes the 4-way
// bank conflict of the old [s*128 + p*16] pattern (34.3M conflicts, 201us):
// p-groups now land on banks {0,16,4,20,8,24,12,28}+4q — conflict-free.
// ---------------------------------------------------------------------------
#define OPS 140  // padded row stride in u32/f32 (128 + 4 per 32)
static __device__ __forceinline__ int swzc(int col) { return col + 4 * (col >> 5); }

__global__ __launch_bounds__(1024) void outproj_kernel(
    const float* __restrict__ Wout, const float* __restrict__ bout,
    u32* __restrict__ io) {
  const int bs = blockIdx.x;  // 2048 blocks
  const int b = bs >> 4;
  const int t0 = (bs & 15) * 64;
  const int tid = threadIdx.x;
  const int p = tid & 7;
  const int vq = tid >> 3;

  __shared__ u32 h1L[64 * OPS];
  __shared__ float outL[64 * OPS];

  const u32* src = io + ((size_t)b * NS + t0) * 128;
  uint4 s0 = *(const uint4*)(src + (size_t)tid * 8);
  uint4 s1 = *(const uint4*)(src + (size_t)tid * 8 + 4);

  u32 wo[16];
  const float* pw = Wout + (size_t)vq * NH + p * 32;
#pragma unroll
  for (int k = 0; k < 8; ++k) {
    float4 w4 = *(const float4*)(pw + 4 * k);
    wo[2 * k] = pkh(w4.x, w4.y); wo[2 * k + 1] = pkh(w4.z, w4.w);
  }
  const float bo = bout[vq];

  {
    const int sr = tid >> 4;                 // row 0..63
    const int sc = (tid & 15) * 8;           // col 0..120, 8-aligned
    const int base = sr * OPS + swzc(sc);    // 16B-aligned (OPS*4=560B, /16 ok)
    *(uint4*)&h1L[base] = s0;
    *(uint4*)&h1L[base + 4] = s1;
  }
  __syncthreads();

#pragma unroll 4
  for (int s = 0; s < 64; ++s) {
    float oa = 0.f;
#pragma unroll
    for (int q = 0; q < 4; ++q) {
      uint4 hq = *(const uint4*)&h1L[s * OPS + swzc(p * 16 + 4 * q)];
      u32 hw[4] = {hq.x, hq.y, hq.z, hq.w};
#pragma unroll
      for (int j = 0; j < 4; ++j) oa = fdot2(wo[4 * q + j], hw[j], oa);
    }
    oa += __shfl_xor(oa, 1);
    oa += __shfl_xor(oa, 2);
    oa += __shfl_xor(oa, 4);
    if (p == 0) outL[s * OPS + swzc(vq)] = oa + bo;
  }
  __syncthreads();

  float* df = (float*)(io + ((size_t)b * NS + t0) * 128);
  {
    const int sr = tid >> 4;
    const int sc = (tid & 15) * 8;
    const int base = sr * OPS + swzc(sc);
    *(float4*)(df + (size_t)tid * 8) = *(float4*)&outL[base];
    *(float4*)(df + (size_t)tid * 8 + 4) = *(float4*)&outL[base + 4];
  }
}

extern "C" void kernel_launch(void* const* d_in, const int* in_sizes, int n_in,
                              void* d_out, int out_size, void* d_ws, size_t ws_size,
                              hipStream_t stream) {
  const float* x    = (const float*)d_in[0];
  const float* Wih0 = (const float*)d_in[1];
  const float* Whh0 = (const float*)d_in[2];
  const float* bih0 = (const float*)d_in[3];
  const float* bhh0 = (const float*)d_in[4];
  const float* Wih1 = (const float*)d_in[5];
  const float* Whh1 = (const float*)d_in[6];
  const float* bih1 = (const float*)d_in[7];
  const float* bhh1 = (const float*)d_in[8];
  const float* Wout = (const float*)d_in[9];
  const float* bout = (const float*)d_in[10];

  // ws (<= 32.5 MiB): xg0 | xg1 | hseed0 | hseed1 | carry0 | carry1
  f16* xg0 = (f16*)d_ws;
  f16* xg1 = (f16*)((char*)d_ws + (16u << 20));
  u32* hseed0 = (u32*)((char*)d_ws + (32u << 20));
  u32* hseed1 = (u32*)((char*)d_ws + (32u << 20) + (64u << 10));
  float* carry0 = (float*)((char*)d_ws + (32u << 20) + (128u << 10));
  float* carry1 = (float*)((char*)d_ws + (32u << 20) + (256u << 10));
  u32* slots = (u32*)d_out;  // h0 -> h1 -> f32 out, in place per chunk row

  // prologue: gemm0(0); scan0(0)
  gemm_pair_kernel<<<512, 512, 0, stream>>>(
      nullptr, nullptr, nullptr, nullptr, nullptr, 0, 0,
      x, Wih0, bih0, bhh0, xg0, 0, 1);
  scan_pair_kernel<<<256, 512, 0, stream>>>(
      nullptr, nullptr, nullptr, nullptr, nullptr, 0, 0, 0,
      xg0, Whh0, slots, hseed0, carry0, 0, 1, 1);

  // pipeline: {gemm1(s) || gemm0(s+1)}; then {scan1(s) || scan0(s+1)}
  for (int s = 0; s < NCH; ++s) {
    const int g0on = (s + 1 < NCH);
    gemm_pair_kernel<<<512, 512, 0, stream>>>(
        slots, Wih1, bih1, bhh1, xg1, s * CH, 1,
        x, Wih0, bih0, bhh0, xg0, (s + 1) * CH, g0on);
    scan_pair_kernel<<<256, 512, 0, stream>>>(
        xg1, Whh1, slots, hseed1, carry1, s * CH, (s == 0) ? 1 : 0, 1,
        xg0, Whh0, slots, hseed0, carry0, (s + 1) * CH, 0, g0on);
  }
  outproj_kernel<<<2048, 1024, 0, stream>>>(Wout, bout, slots);
}

// Round 12
// 4568.657 us; speedup vs baseline: 1.3046x; 1.0763x over previous
//
#include <hip/hip_runtime.h>
#include <cstdint>

#define NB 128   // batch
#define NS 1024  // seq len
#define NV 128   // input dim
#define NH 256   // hidden
#define CH 64    // chunk length
#define NCH (NS / CH)

typedef _Float16 f16;
typedef _Float16 h2 __attribute__((ext_vector_type(2)));
typedef uint32_t u32;

static __device__ __forceinline__ float fdot2(u32 a, u32 b, float c) {
  return __builtin_amdgcn_fdot2(__builtin_bit_cast(h2, a),
                                __builtin_bit_cast(h2, b), c, false);
}
static __device__ __forceinline__ u32 pkh(float a, float b) {  // RTN
  union { h2 h; u32 u; } cv; cv.h = h2{(f16)a, (f16)b}; return cv.u;
}
static __device__ __forceinline__ u32 pkz(float a, float b) {  // RTZ (x only)
  return __builtin_bit_cast(u32, __builtin_amdgcn_cvt_pkrtz(a, b));
}
static __device__ __forceinline__ float sigm(float x) { return 1.f / (1.f + __expf(-x)); }
static __device__ __forceinline__ float tanh_(float x) { return 1.f - 2.f / (__expf(2.f * x) + 1.f); }

// Opaque asm def: allocator cannot rematerialize -> weight packs stay resident.
static __device__ __forceinline__ void pin4(uint4& v) {
  asm volatile("" : "+v"(v.x), "+v"(v.y), "+v"(v.z), "+v"(v.w));
}

// ---------------------------------------------------------------------------
// prepack: all four weight matrices f32 -> packed f16 pairs, ONCE per call.
// Removes the per-dispatch 1MB L2 re-read + ~128 v_cvt_pk/thread from every
// gemm/scan preamble (17 dispatches each). pkh = same values as before.
// Segments (u32 counts): Wih0p 65536 | Wih1p 131072 | Whh0p 131072 | Whh1p 131072.
// ---------------------------------------------------------------------------
__global__ __launch_bounds__(1024) void prepack_kernel(
    const float* __restrict__ Wih0, const float* __restrict__ Wih1,
    const float* __restrict__ Whh0, const float* __restrict__ Whh1,
    u32* __restrict__ Wih0p, u32* __restrict__ Wih1p,
    u32* __restrict__ Whh0p, u32* __restrict__ Whh1p) {
  const int g = blockIdx.x * 1024 + threadIdx.x;  // 448 blocks = 458752 u32
  const float* src; u32* dst; int off;
  if (g < 65536)       { src = Wih0; dst = Wih0p; off = g; }
  else if (g < 196608) { src = Wih1; dst = Wih1p; off = g - 65536; }
  else if (g < 327680) { src = Whh0; dst = Whh0p; off = g - 196608; }
  else                 { src = Whh1; dst = Whh1p; off = g - 327680; }
  dst[off] = pkh(src[2 * off], src[2 * off + 1]);
}

// ---------------------------------------------------------------------------
// gemm pair. NEW vs r11: (a) weights loaded pre-packed (half bytes, no cvt);
// (b) the 32-timestep input panel staged to LDS once (coalesced), k-loop reads
// it via UNIFORM-address ds_read_b128 broadcast -> no L2 latency in the inner
// loop (this was the 176us: VALUBusy 38%, Occ 21%, vmcnt-stalled on xv loads).
//  blocks [0,256):  gemm1(s): thread owns rows tid,tid+512; 24 reg + 8 LDS.
//  blocks [256,512): gemm0(s+1): 16 uint4/row pinned; x packed during staging.
// ---------------------------------------------------------------------------
__global__ __attribute__((amdgpu_flat_work_group_size(512, 512),
                          amdgpu_waves_per_eu(2, 2)))
void gemm_pair_kernel(
    const u32* __restrict__ g1_in, const u32* __restrict__ g1_Wp,
    const float* __restrict__ g1_bih, const float* __restrict__ g1_bhh,
    f16* __restrict__ g1_xg, int g1_t0, int g1_on,
    const float* __restrict__ g0_x, const u32* __restrict__ g0_Wp,
    const float* __restrict__ g0_bih, const float* __restrict__ g0_bhh,
    f16* __restrict__ g0_xg, int g0_t0, int g0_on) {
  __shared__ uint4 wL0[8][512];
  __shared__ uint4 wL1[8][512];
  __shared__ __align__(16) u32 panel[32 * 128];  // 16 KiB input panel
  const int blk = blockIdx.x;
  const int tid = threadIdx.x;
  const int r0 = tid, r1 = tid + 512;

  if (blk < 256) {
    if (!g1_on) return;
    const int b = blk >> 1, tpart = blk & 1;
    // stage 32 timesteps of h0 (16 KiB contiguous) -> LDS
    const uint4* src = (const uint4*)(g1_in + ((size_t)b * NS + g1_t0 + tpart * 32) * 128);
    ((uint4*)panel)[tid] = src[tid];
    ((uint4*)panel)[tid + 512] = src[tid + 512];
    // packed weights: 32 uint4/row
    uint4 w0r[24], w1r[24];
    {
      const u32* p0 = g1_Wp + (size_t)r0 * 128;
      const u32* p1 = g1_Wp + (size_t)r1 * 128;
#pragma unroll
      for (int k = 0; k < 32; ++k) {
        uint4 v0 = *(const uint4*)(p0 + 4 * k);
        uint4 v1 = *(const uint4*)(p1 + 4 * k);
        if (k < 24) { w0r[k] = v0; w1r[k] = v1; }
        else { wL0[k - 24][tid] = v0; wL1[k - 24][tid] = v1; }
      }
    }
#pragma unroll
    for (int k = 0; k < 24; ++k) { pin4(w0r[k]); pin4(w1r[k]); }
    const float bs0 = g1_bih[r0] + g1_bhh[r0];
    const float bs1 = g1_bih[r1] + g1_bhh[r1];
    __syncthreads();
#pragma unroll 1
    for (int tl = 0; tl < 32; ++tl) {
      float a0 = 0.f, a1 = 0.f;
#pragma unroll
      for (int k = 0; k < 32; ++k) {
        uint4 xv = *(const uint4*)&panel[tl * 128 + 4 * k];  // uniform broadcast
        uint4 wa = (k < 24) ? w0r[k] : wL0[k - 24][tid];
        uint4 wb = (k < 24) ? w1r[k] : wL1[k - 24][tid];
        a0 = fdot2(wa.x, xv.x, a0); a0 = fdot2(wa.y, xv.y, a0);
        a0 = fdot2(wa.z, xv.z, a0); a0 = fdot2(wa.w, xv.w, a0);
        a1 = fdot2(wb.x, xv.x, a1); a1 = fdot2(wb.y, xv.y, a1);
        a1 = fdot2(wb.z, xv.z, a1); a1 = fdot2(wb.w, xv.w, a1);
      }
      f16* op = g1_xg + ((size_t)b * CH + tpart * 32 + tl) * 1024;
      op[r0] = (f16)(a0 + bs0);
      op[r1] = (f16)(a1 + bs1);
    }
  } else {
    if (!g0_on) return;
    const int idx = blk - 256;
    const int b = idx >> 1, tpart = idx & 1;
    // stage 32 timesteps of x, packed f32->f16 during the copy (8 KiB LDS)
    {
      const float4* src = (const float4*)(g0_x + ((size_t)b * NS + g0_t0 + tpart * 32) * NV);
      float4 a = src[2 * tid];
      float4 c = src[2 * tid + 1];
      ((uint4*)panel)[tid] = uint4{pkz(a.x, a.y), pkz(a.z, a.w), pkz(c.x, c.y), pkz(c.z, c.w)};
    }
    uint4 w0r[16], w1r[16];
    {
      const u32* p0 = g0_Wp + (size_t)r0 * 64;
      const u32* p1 = g0_Wp + (size_t)r1 * 64;
#pragma unroll
      for (int k = 0; k < 16; ++k) {
        w0r[k] = *(const uint4*)(p0 + 4 * k);
        w1r[k] = *(const uint4*)(p1 + 4 * k);
      }
    }
#pragma unroll
    for (int k = 0; k < 16; ++k) { pin4(w0r[k]); pin4(w1r[k]); }
    const float bs0 = g0_bih[r0] + g0_bhh[r0];
    const float bs1 = g0_bih[r1] + g0_bhh[r1];
    __syncthreads();
#pragma unroll 1
    for (int tl = 0; tl < 32; ++tl) {
      float a0 = 0.f, a1 = 0.f;
#pragma unroll
      for (int k = 0; k < 16; ++k) {
        uint4 xv = *(const uint4*)&panel[tl * 64 + 4 * k];  // uniform broadcast
        a0 = fdot2(w0r[k].x, xv.x, a0); a0 = fdot2(w0r[k].y, xv.y, a0);
        a0 = fdot2(w0r[k].z, xv.z, a0); a0 = fdot2(w0r[k].w, xv.w, a0);
        a1 = fdot2(w1r[k].x, xv.x, a1); a1 = fdot2(w1r[k].y, xv.y, a1);
        a1 = fdot2(w1r[k].z, xv.z, a1); a1 = fdot2(w1r[k].w, xv.w, a1);
      }
      f16* op = g0_xg + ((size_t)b * CH + tpart * 32 + tl) * 1024;
      op[r0] = (f16)(a0 + bs0);
      op[r1] = (f16)(a1 + bs1);
    }
  }
}

// ---------------------------------------------------------------------------
// scan pair (r11 body — uniform ds_read_b128 h-broadcast, tid-indexed wL,
// pin4). Only change: weights loaded pre-packed (preamble L2 traffic halved).
//  blocks [0,128) = scan1 chunk s; [128,256) = scan0 chunk s+1. 1 WG/CU.
// ---------------------------------------------------------------------------
__global__ __attribute__((amdgpu_flat_work_group_size(512, 512),
                          amdgpu_waves_per_eu(2, 2)))
void scan_pair_kernel(
    const f16* __restrict__ xgA, const u32* __restrict__ WhhAp,
    u32* __restrict__ slotsA, u32* __restrict__ hseedA, float* __restrict__ carryA,
    int t0A, int firstA, int onA,
    const f16* __restrict__ xgB, const u32* __restrict__ WhhBp,
    u32* __restrict__ slotsB, u32* __restrict__ hseedB, float* __restrict__ carryB,
    int t0B, int firstB, int onB) {
  __shared__ uint4 wL0[8][512];                 // r0-row overflow, tid-indexed
  __shared__ uint4 wL1[8][512];                 // r1-row overflow, tid-indexed
  __shared__ __align__(16) u32 hbuf[2][128];    // h as 256 f16, double-buffered

  const int blk = blockIdx.x;
  const int tid = threadIdx.x;
  const f16* xg; const u32* Whhp; u32* slots; u32* hseed; float* carry;
  int t0, first, b;
  if (blk < 128) {
    if (!onA) return;
    b = blk; xg = xgA; Whhp = WhhAp; slots = slotsA; hseed = hseedA; carry = carryA;
    t0 = t0A; first = firstA;
  } else {
    if (!onB) return;
    b = blk - 128; xg = xgB; Whhp = WhhBp; slots = slotsB; hseed = hseedB; carry = carryB;
    t0 = t0B; first = firstB;
  }
  const int p = tid & 1;
  const int u = tid >> 1;
  const int r0 = p * 256 + u;   // gate i (p=0) / f (p=1)
  const int r1 = r0 + 512;      // gate g (p=0) / o (p=1)

  uint4 w0r[24], w1r[24];
  {
    const u32* p0 = Whhp + (size_t)r0 * 128;
    const u32* p1 = Whhp + (size_t)r1 * 128;
#pragma unroll
    for (int k = 0; k < 32; ++k) {
      uint4 v0 = *(const uint4*)(p0 + 4 * k);
      uint4 v1 = *(const uint4*)(p1 + 4 * k);
      if (k < 24) { w0r[k] = v0; w1r[k] = v1; }
      else { wL0[k - 24][tid] = v0; wL1[k - 24][tid] = v1; }
    }
  }
#pragma unroll
  for (int k = 0; k < 24; ++k) { pin4(w0r[k]); pin4(w1r[k]); }
  float c;
  if (first) {
    if (tid < 128) hbuf[0][tid] = 0u;
    c = 0.f;
  } else {
    if (tid < 128) hbuf[0][tid] = hseed[b * 128 + tid];
    c = carry[b * 256 + u];
  }
  __syncthreads();

#pragma unroll 1
  for (int tl = 0; tl < CH; ++tl) {
    const int cur = tl & 1, nxt = cur ^ 1;
    const f16* xp = xg + ((size_t)b * CH + tl) * 1024;
    const float xa = (float)xp[r0];
    const float xb = (float)xp[r1];

    float a0 = 0.f, a1 = 0.f;
#pragma unroll
    for (int k = 0; k < 32; ++k) {
      uint4 hk = *(const uint4*)&hbuf[cur][4 * k];  // uniform addr -> broadcast
      const uint4 wa = (k < 24) ? w0r[k] : wL0[k - 24][tid];
      const uint4 wb = (k < 24) ? w1r[k] : wL1[k - 24][tid];
      a0 = fdot2(wa.x, hk.x, a0); a0 = fdot2(wa.y, hk.y, a0);
      a0 = fdot2(wa.z, hk.z, a0); a0 = fdot2(wa.w, hk.w, a0);
      a1 = fdot2(wb.x, hk.x, a1); a1 = fdot2(wb.y, hk.y, a1);
      a1 = fdot2(wb.z, hk.z, a1); a1 = fdot2(wb.w, hk.w, a1);
    }
    a0 += xa; a1 += xb;
    const float px0 = __shfl_xor(a0, 1);   // partner lane: other two gates
    const float px1 = __shfl_xor(a1, 1);
    const float ai = p ? px0 : a0;
    const float ag = p ? px1 : a1;
    const float af = p ? a0 : px0;
    const float ao = p ? a1 : px1;
    const float gi = sigm(ai), gg = tanh_(ag), gf = sigm(af), go = sigm(ao);
    c = gf * c + gi * gg;                  // redundant in both lanes (same value)
    const float h = go * tanh_(c);
    if (p == 0) {
      ((f16*)hbuf[nxt])[u] = (f16)h;
      ((f16*)(slots + ((size_t)b * NS + t0 + tl) * 128))[u] = (f16)h;
    }
    __syncthreads();  // single barrier: h(t) visible for next step
  }
  if (tid < 128) hseed[b * 128 + tid] = hbuf[0][tid];  // CH even -> final in [0]
  if (p == 0) carry[b * 256 + u] = c;
}

// ---------------------------------------------------------------------------
// outproj: out = Wout·h1 + b, IN PLACE over d_out slots. r11 version
// (fine-grained padding col+4*(col>>5), conflict-free). Unchanged.
// ---------------------------------------------------------------------------
#define OPS 140
static __device__ __forceinline__ int swzc(int col) { return col + 4 * (col >> 5); }

__global__ __launch_bounds__(1024) void outproj_kernel(
    const float* __restrict__ Wout, const float* __restrict__ bout,
    u32* __restrict__ io) {
  const int bs = blockIdx.x;  // 2048 blocks
  const int b = bs >> 4;
  const int t0 = (bs & 15) * 64;
  const int tid = threadIdx.x;
  const int p = tid & 7;
  const int vq = tid >> 3;

  __shared__ u32 h1L[64 * OPS];
  __shared__ float outL[64 * OPS];

  const u32* src = io + ((size_t)b * NS + t0) * 128;
  uint4 s0 = *(const uint4*)(src + (size_t)tid * 8);
  uint4 s1 = *(const uint4*)(src + (size_t)tid * 8 + 4);

  u32 wo[16];
  const float* pw = Wout + (size_t)vq * NH + p * 32;
#pragma unroll
  for (int k = 0; k < 8; ++k) {
    float4 w4 = *(const float4*)(pw + 4 * k);
    wo[2 * k] = pkh(w4.x, w4.y); wo[2 * k + 1] = pkh(w4.z, w4.w);
  }
  const float bo = bout[vq];

  {
    const int sr = tid >> 4;
    const int sc = (tid & 15) * 8;
    const int base = sr * OPS + swzc(sc);
    *(uint4*)&h1L[base] = s0;
    *(uint4*)&h1L[base + 4] = s1;
  }
  __syncthreads();

#pragma unroll 4
  for (int s = 0; s < 64; ++s) {
    float oa = 0.f;
#pragma unroll
    for (int q = 0; q < 4; ++q) {
      uint4 hq = *(const uint4*)&h1L[s * OPS + swzc(p * 16 + 4 * q)];
      u32 hw[4] = {hq.x, hq.y, hq.z, hq.w};
#pragma unroll
      for (int j = 0; j < 4; ++j) oa = fdot2(wo[4 * q + j], hw[j], oa);
    }
    oa += __shfl_xor(oa, 1);
    oa += __shfl_xor(oa, 2);
    oa += __shfl_xor(oa, 4);
    if (p == 0) outL[s * OPS + swzc(vq)] = oa + bo;
  }
  __syncthreads();

  float* df = (float*)(io + ((size_t)b * NS + t0) * 128);
  {
    const int sr = tid >> 4;
    const int sc = (tid & 15) * 8;
    const int base = sr * OPS + swzc(sc);
    *(float4*)(df + (size_t)tid * 8) = *(float4*)&outL[base];
    *(float4*)(df + (size_t)tid * 8 + 4) = *(float4*)&outL[base + 4];
  }
}

extern "C" void kernel_launch(void* const* d_in, const int* in_sizes, int n_in,
                              void* d_out, int out_size, void* d_ws, size_t ws_size,
                              hipStream_t stream) {
  const float* x    = (const float*)d_in[0];
  const float* Wih0 = (const float*)d_in[1];
  const float* Whh0 = (const float*)d_in[2];
  const float* bih0 = (const float*)d_in[3];
  const float* bhh0 = (const float*)d_in[4];
  const float* Wih1 = (const float*)d_in[5];
  const float* Whh1 = (const float*)d_in[6];
  const float* bih1 = (const float*)d_in[7];
  const float* bhh1 = (const float*)d_in[8];
  const float* Wout = (const float*)d_in[9];
  const float* bout = (const float*)d_in[10];

  // ws (< 38 MiB): xg0 | xg1 | hseed/carry | packed weights
  f16* xg0 = (f16*)d_ws;
  f16* xg1 = (f16*)((char*)d_ws + (16u << 20));
  u32* hseed0 = (u32*)((char*)d_ws + (32u << 20));
  u32* hseed1 = (u32*)((char*)d_ws + (32u << 20) + (64u << 10));
  float* carry0 = (float*)((char*)d_ws + (32u << 20) + (128u << 10));
  float* carry1 = (float*)((char*)d_ws + (32u << 20) + (256u << 10));
  u32* Wih0p = (u32*)((char*)d_ws + (34u << 20));
  u32* Wih1p = (u32*)((char*)d_ws + (35u << 20));
  u32* Whh0p = (u32*)((char*)d_ws + (36u << 20));
  u32* Whh1p = (u32*)((char*)d_ws + (37u << 20));
  u32* slots = (u32*)d_out;  // h0 -> h1 -> f32 out, in place per chunk row

  prepack_kernel<<<448, 1024, 0, stream>>>(Wih0, Wih1, Whh0, Whh1,
                                           Wih0p, Wih1p, Whh0p, Whh1p);

  // prologue: gemm0(0); scan0(0)
  gemm_pair_kernel<<<512, 512, 0, stream>>>(
      nullptr, nullptr, nullptr, nullptr, nullptr, 0, 0,
      x, Wih0p, bih0, bhh0, xg0, 0, 1);
  scan_pair_kernel<<<256, 512, 0, stream>>>(
      nullptr, nullptr, nullptr, nullptr, nullptr, 0, 0, 0,
      xg0, Whh0p, slots, hseed0, carry0, 0, 1, 1);

  // pipeline: {gemm1(s) || gemm0(s+1)}; then {scan1(s) || scan0(s+1)}
  for (int s = 0; s < NCH; ++s) {
    const int g0on = (s + 1 < NCH);
    gemm_pair_kernel<<<512, 512, 0, stream>>>(
        slots, Wih1p, bih1, bhh1, xg1, s * CH, 1,
        x, Wih0p, bih0, bhh0, xg0, (s + 1) * CH, g0on);
    scan_pair_kernel<<<256, 512, 0, stream>>>(
        xg1, Whh1p, slots, hseed1, carry1, s * CH, (s == 0) ? 1 : 0, 1,
        xg0, Whh0p, slots, hseed0, carry0, (s + 1) * CH, 0, g0on);
  }
  outproj_kernel<<<2048, 1024, 0, stream>>>(Wout, bout, slots);
}